// Round 4
// baseline (342.874 us; speedup 1.0000x reference)
//
#include <hip/hip_runtime.h>
#include <hip/hip_bf16.h>
#include <hip/hip_fp16.h>
#include <stdint.h>

#define M_DIM 4096   // B*S = 2*2048
#define N_DIM 4096   // O
#define K_DIM 4096   // I
#define GROUPSZ 128
#define MAXQ 15.0f

#define BM 256
#define BN 256
#define BK 64
#define T_TILES (K_DIM / BK)   // 64

typedef __attribute__((ext_vector_type(8))) short short8;
typedef __attribute__((ext_vector_type(4))) float f32x4;

// ---------------- quant: groupwise asymmetric fake-quant, f32 -> bf16 ----------------
__global__ __launch_bounds__(256) void quant_kernel(
    const float* __restrict__ weight, const float* __restrict__ value,
    const float* __restrict__ min_scale, const float* __restrict__ max_scale,
    __hip_bfloat16* __restrict__ wq)
{
    const int tid  = threadIdx.x;
    const int wave = tid >> 6;
    const int lane = tid & 63;
    const long g    = (long)blockIdx.x * 4 + wave;
    const long base = g * GROUPSZ + lane * 2;

    const float2 w = *(const float2*)(weight + base);
    const float2 v = *(const float2*)(value  + base);

    float mn = fminf(w.x, w.y);
    float mx = fmaxf(w.x, w.y);
#pragma unroll
    for (int off = 32; off >= 1; off >>= 1) {
        mn = fminf(mn, __shfl_xor(mn, off, 64));
        mx = fmaxf(mx, __shfl_xor(mx, off, 64));
    }
    mn = fminf(mn, 0.0f);
    mx = fmaxf(mx, 0.0f);

    const float ms = fminf(fmaxf(min_scale[g], -1.0f), 0.0f) + 1.0f;
    const float xs = fminf(fmaxf(max_scale[g], -1.0f), 0.0f) + 1.0f;
    float wmin = mn * ms;
    float wmax = mx * xs;
    if (wmin == 0.0f && wmax == 0.0f) { wmin = -1.0f; wmax = 1.0f; }

    const float scale = (float)(_Float16)((wmax - wmin) / MAXQ);
    const float zp    = rintf(-wmin / scale);

    const float q0 = fminf(fmaxf(rintf(w.x / scale + v.x) + zp, 0.0f), MAXQ);
    const float q1 = fminf(fmaxf(rintf(w.y / scale + v.y) + zp, 0.0f), MAXQ);
    const float o0 = scale * (q0 - zp);
    const float o1 = scale * (q1 - zp);

    __hip_bfloat162 o;
    o.x = __float2bfloat16(o0);
    o.y = __float2bfloat16(o1);
    *(__hip_bfloat162*)(wq + base) = o;
}

// ---------------- x cast: f32 -> bf16, 8 elems/thread ----------------
__global__ __launch_bounds__(256) void cast_kernel(
    const float* __restrict__ x, __hip_bfloat16* __restrict__ xb)
{
    const long i = ((long)blockIdx.x * 256 + threadIdx.x) * 8;
    const float4 a = *(const float4*)(x + i);
    const float4 b = *(const float4*)(x + i + 4);
    union { short8 s; __hip_bfloat16 h[8]; } u;
    u.h[0] = __float2bfloat16(a.x);
    u.h[1] = __float2bfloat16(a.y);
    u.h[2] = __float2bfloat16(a.z);
    u.h[3] = __float2bfloat16(a.w);
    u.h[4] = __float2bfloat16(b.x);
    u.h[5] = __float2bfloat16(b.y);
    u.h[6] = __float2bfloat16(b.z);
    u.h[7] = __float2bfloat16(b.w);
    *(short8*)(xb + i) = u.s;
}

// ---------------- GEMM: 256x256, BK=64, 8 waves, register-pipelined 4-phase ----------------
// C[m][n] = sum_k A[m][k]*B[n][k] + bias[n]
// ds_reads issued one phase ahead of use (counted lgkmcnt, never 0 in steady state),
// so LDS drain hides under the previous phase's MFMA cluster. One barrier per phase.
__global__ __launch_bounds__(512, 2) void gemm_kernel(
    const __hip_bfloat16* __restrict__ A,   // [M][K] bf16 (x)
    const __hip_bfloat16* __restrict__ B,   // [N][K] bf16 (wq)
    const float* __restrict__ bias,
    float* __restrict__ C)                  // [M][N] f32
{
    __shared__ __align__(16) char lds[131072];
    // A buf c: [c*32768, +32768); B buf c: [65536 + c*32768, +32768)
    // row r at r*128 bytes; 16B slot s holds logical slot s ^ (r&7).

    const int tid  = threadIdx.x;
    const int lane = tid & 63;
    const int wv   = tid >> 6;
    const int wm   = wv >> 2;          // 2 (M) x 4 (N) wave grid
    const int wn   = wv & 3;

    const int bid = blockIdx.x;
    const int swz = (bid & 7) * (gridDim.x >> 3) + (bid >> 3);
    const int brow = (swz >> 4) * BM;
    const int bcol = (swz & 15) * BN;

    const int stg_r = tid >> 3;
    const int cc    = ((tid & 7) ^ (stg_r & 7)) * 8;

#define STAGE(XP, rowbase, h, tau, ldsbase)                                         \
    { _Pragma("unroll")                                                             \
      for (int inst = 0; inst < 2; ++inst) {                                        \
        const __hip_bfloat16* g = (XP) +                                            \
            (size_t)((rowbase) + (h) * 128 + inst * 64 + stg_r) * K_DIM +           \
            (tau) * 64 + cc;                                                        \
        __builtin_amdgcn_global_load_lds(                                           \
            (const __attribute__((address_space(1))) void*)g,                       \
            (__attribute__((address_space(3))) void*)(lds + (ldsbase) +             \
                (h) * 16384 + inst * 8192 + (wv << 10)),                            \
            16, 0, 0);                                                              \
      } }

    const int ro = lane & 15;
    const int hi = lane >> 4;
    const int slot0 = ((0 + hi) ^ (ro & 7)) << 4;
    const int slot1 = ((4 + hi) ^ (ro & 7)) << 4;
    const int rbA = (wm * 128 + ro) * 128;
    const int rbB = (wn * 64  + ro) * 128;

    f32x4 acc[8][4] = {};
    short8 bR0[4][2], bR1[4][2];     // B(t) fragment double-buffer (rotates)
    short8 aP0[2][2], aP1[2][2];     // A m0,m1 prefetch double-buffer

#define MFMA16(M0, BIN, X0, X1)                                                     \
    { _Pragma("unroll")                                                             \
      for (int n = 0; n < 4; ++n) {                                                 \
        acc[M0][n]     = __builtin_amdgcn_mfma_f32_16x16x32_bf16((X0)[0], BIN[n][0], acc[M0][n],     0, 0, 0); \
        acc[M0 + 1][n] = __builtin_amdgcn_mfma_f32_16x16x32_bf16((X1)[0], BIN[n][0], acc[M0 + 1][n], 0, 0, 0); \
      }                                                                             \
      _Pragma("unroll")                                                             \
      for (int n = 0; n < 4; ++n) {                                                 \
        acc[M0][n]     = __builtin_amdgcn_mfma_f32_16x16x32_bf16((X0)[1], BIN[n][1], acc[M0][n],     0, 0, 0); \
        acc[M0 + 1][n] = __builtin_amdgcn_mfma_f32_16x16x32_bf16((X1)[1], BIN[n][1], acc[M0 + 1][n], 0, 0, 0); \
      } }

#define LDA2(dst, m)                                                                \
    dst[0] = *(const short8*)(bA_ + (m) * 2048 + slot0);                            \
    dst[1] = *(const short8*)(bA_ + (m) * 2048 + slot1);

    // prologue: stage B(0), A(0), B(1); wait tile0; prefetch B(0)+A01(0) to regs
    STAGE(B, bcol, 0, 0, 65536);
    STAGE(B, bcol, 1, 0, 65536);
    STAGE(A, brow, 0, 0, 0);
    STAGE(A, brow, 1, 0, 0);
    STAGE(B, bcol, 0, 1, 65536 + 32768);
    STAGE(B, bcol, 1, 1, 65536 + 32768);
    asm volatile("s_waitcnt vmcnt(4)" ::: "memory");   // leaves B(1) in flight
    __builtin_amdgcn_s_barrier();
    {
        const char* bB_ = lds + 65536 + rbB;
        const char* bA_ = lds + rbA;
#pragma unroll
        for (int n = 0; n < 4; ++n) {
            bR0[n][0] = *(const short8*)(bB_ + n * 2048 + slot0);
            bR0[n][1] = *(const short8*)(bB_ + n * 2048 + slot1);
        }
        LDA2(aP0[0], 0); LDA2(aP0[1], 1);
    }

    // Per tile t (buffer c=t&1):
    //  P1: read A23; stage A(t+1)->c^1; lgkm(4);  MFMA m0,m1 (uses prefetched B,A01); bar
    //  P2: read A45; stage B(t+2)h0->c; lgkm(4);  MFMA m2,m3; bar
    //  P3: read A67; stage B(t+2)h1->c; lgkm(4);  MFMA m4,m5; vmcnt(4|0); bar
    //  P4: read B(t+1)[8]+A01(t+1)[4] from c^1; lgkm(12|0); MFMA m6,m7; bar
#define TILE_BODY(T_, BIN, BOUT, AIN, AOUT)                                         \
    {                                                                               \
        const int t_ = (T_);                                                        \
        const int c_ = t_ & 1;                                                      \
        const char* bA_  = lds + c_ * 32768 + rbA;                                  \
        const char* bAn_ = lds + (c_ ^ 1) * 32768 + rbA;                            \
        const char* bBn_ = lds + 65536 + (c_ ^ 1) * 32768 + rbB;                    \
        short8 a23[2][2], a45[2][2], a67[2][2];                                     \
        /* P1 */                                                                    \
        LDA2(a23[0], 2); LDA2(a23[1], 3);                                           \
        if (t_ + 1 < T_TILES) {                                                     \
            STAGE(A, brow, 0, t_ + 1, (c_ ^ 1) * 32768);                            \
            STAGE(A, brow, 1, t_ + 1, (c_ ^ 1) * 32768);                            \
        }                                                                           \
        asm volatile("s_waitcnt lgkmcnt(4)" ::: "memory");                          \
        __builtin_amdgcn_s_setprio(1);                                              \
        MFMA16(0, BIN, AIN[0], AIN[1]);                                             \
        __builtin_amdgcn_s_setprio(0);                                              \
        __builtin_amdgcn_s_barrier();                                               \
        /* P2 */                                                                    \
        LDA2(a45[0], 4); LDA2(a45[1], 5);                                           \
        if (t_ + 2 < T_TILES) { STAGE(B, bcol, 0, t_ + 2, 65536 + c_ * 32768); }    \
        asm volatile("s_waitcnt lgkmcnt(4)" ::: "memory");                          \
        __builtin_amdgcn_s_setprio(1);                                              \
        MFMA16(2, BIN, a23[0], a23[1]);                                             \
        __builtin_amdgcn_s_setprio(0);                                              \
        __builtin_amdgcn_s_barrier();                                               \
        /* P3 */                                                                    \
        LDA2(a67[0], 6); LDA2(a67[1], 7);                                           \
        if (t_ + 2 < T_TILES) { STAGE(B, bcol, 1, t_ + 2, 65536 + c_ * 32768); }    \
        asm volatile("s_waitcnt lgkmcnt(4)" ::: "memory");                          \
        __builtin_amdgcn_s_setprio(1);                                              \
        MFMA16(4, BIN, a45[0], a45[1]);                                             \
        __builtin_amdgcn_s_setprio(0);                                              \
        if (t_ + 2 < T_TILES)      { asm volatile("s_waitcnt vmcnt(4)" ::: "memory"); } \
        else if (t_ + 1 < T_TILES) { asm volatile("s_waitcnt vmcnt(0)" ::: "memory"); } \
        __builtin_amdgcn_s_barrier();                                               \
        /* P4 */                                                                    \
        if (t_ + 1 < T_TILES) {                                                     \
            _Pragma("unroll")                                                       \
            for (int n = 0; n < 4; ++n) {                                           \
                BOUT[n][0] = *(const short8*)(bBn_ + n * 2048 + slot0);             \
                BOUT[n][1] = *(const short8*)(bBn_ + n * 2048 + slot1);             \
            }                                                                       \
            { const char* bA_ = bAn_;                                               \
              LDA2(AOUT[0], 0); LDA2(AOUT[1], 1); }                                 \
            asm volatile("s_waitcnt lgkmcnt(12)" ::: "memory");                     \
        } else {                                                                    \
            asm volatile("s_waitcnt lgkmcnt(0)" ::: "memory");                      \
        }                                                                           \
        __builtin_amdgcn_s_setprio(1);                                              \
        MFMA16(6, BIN, a67[0], a67[1]);                                             \
        __builtin_amdgcn_s_setprio(0);                                              \
        __builtin_amdgcn_s_barrier();                                               \
    }

    for (int tt = 0; tt < T_TILES; tt += 2) {
        TILE_BODY(tt,     bR0, bR1, aP0, aP1);
        TILE_BODY(tt + 1, bR1, bR0, aP1, aP0);
    }

    // epilogue: C/D frag layout col = lane&15, row = hi*4 + reg
    const int col   = lane & 15;
    const int rbase = hi * 4;
    float bv[4];
#pragma unroll
    for (int n = 0; n < 4; ++n)
        bv[n] = bias[bcol + wn * 64 + n * 16 + col];

#pragma unroll
    for (int m = 0; m < 8; ++m) {
        const int mrow = brow + wm * 128 + m * 16 + rbase;
#pragma unroll
        for (int r = 0; r < 4; ++r) {
            float* crow = C + (size_t)(mrow + r) * N_DIM + bcol + wn * 64 + col;
#pragma unroll
            for (int n = 0; n < 4; ++n)
                crow[n * 16] = acc[m][n][r] + bv[n];
        }
    }
#undef STAGE
#undef MFMA16
#undef LDA2
#undef TILE_BODY
}

extern "C" void kernel_launch(void* const* d_in, const int* in_sizes, int n_in,
                              void* d_out, int out_size, void* d_ws, size_t ws_size,
                              hipStream_t stream) {
    const float* x         = (const float*)d_in[0];
    const float* weight    = (const float*)d_in[1];
    const float* bias      = (const float*)d_in[2];
    const float* value     = (const float*)d_in[3];
    const float* min_scale = (const float*)d_in[4];
    const float* max_scale = (const float*)d_in[5];
    float* out = (float*)d_out;

    __hip_bfloat16* xb  = (__hip_bfloat16*)d_ws;                       // [M][K] bf16
    __hip_bfloat16* wqb = xb + (size_t)M_DIM * K_DIM;                  // [N][K] bf16

    quant_kernel<<<(N_DIM * K_DIM / GROUPSZ) / 4, 256, 0, stream>>>(
        weight, value, min_scale, max_scale, wqb);
    cast_kernel<<<(M_DIM * K_DIM) / (256 * 8), 256, 0, stream>>>(x, xb);
    gemm_kernel<<<(M_DIM / BM) * (N_DIM / BN), 512, 0, stream>>>(xb, wqb, bias, out);
}